// Round 14
// baseline (1445.162 us; speedup 1.0000x reference)
//
#include <hip/hip_runtime.h>

#define LEAKY(v) ((v) > 0.f ? (v) : 0.2f * (v))

// ======================= pos-bias MLP (961 rows, tiny) =======================
__device__ __forceinline__ void ln_relu11(float* p, const float* __restrict__ g,
                                          const float* __restrict__ b) {
  float mu = 0.f;
#pragma unroll
  for (int j = 0; j < 11; ++j) mu += p[j];
  mu *= (1.f / 11.f);
  float var = 0.f;
#pragma unroll
  for (int j = 0; j < 11; ++j) { float d = p[j] - mu; var += d * d; }
  var *= (1.f / 11.f);
  float inv = 1.f / sqrtf(var + 1e-5f);
#pragma unroll
  for (int j = 0; j < 11; ++j) {
    float v = (p[j] - mu) * inv * g[j] + b[j];
    p[j] = v > 0.f ? v : 0.f;
  }
}

__global__ void pos_mlp_kernel(
    const float* __restrict__ w0, const float* __restrict__ b0,
    const float* __restrict__ g1, const float* __restrict__ be1,
    const float* __restrict__ w1, const float* __restrict__ b1,
    const float* __restrict__ g2, const float* __restrict__ be2,
    const float* __restrict__ w2, const float* __restrict__ b2,
    const float* __restrict__ g3, const float* __restrict__ be3,
    const float* __restrict__ w3, const float* __restrict__ b3,
    float* __restrict__ pos_out) {
  int r = blockIdx.x * 256 + threadIdx.x;
  if (r >= 961) return;
  float bh = (float)(r / 31 - 15);
  float bw = (float)(r % 31 - 15);
  float p[11], q[11];
#pragma unroll
  for (int j = 0; j < 11; ++j) p[j] = bh * w0[2 * j] + bw * w0[2 * j + 1] + b0[j];
  ln_relu11(p, g1, be1);
#pragma unroll
  for (int j = 0; j < 11; ++j) {
    float s = b1[j];
#pragma unroll
    for (int k = 0; k < 11; ++k) s += p[k] * w1[j * 11 + k];
    q[j] = s;
  }
  ln_relu11(q, g2, be2);
#pragma unroll
  for (int j = 0; j < 11; ++j) {
    float s = b2[j];
#pragma unroll
    for (int k = 0; k < 11; ++k) s += q[k] * w2[j * 11 + k];
    p[j] = s;
  }
  ln_relu11(p, g3, be3);
#pragma unroll
  for (int n = 0; n < 6; ++n) {
    float s = b3[n];
#pragma unroll
    for (int k = 0; k < 11; ++k) s += p[k] * w3[n * 11 + k];
    pos_out[r * 6 + n] = s;
  }
}

// rpb[n][l][m] = mean over 2x2 of pos[rel_idx][n]   (6*256*64 elements)
__global__ void rpb_kernel(const float* __restrict__ pos, float* __restrict__ rpb) {
  int o = blockIdx.x * 256 + threadIdx.x;  // < 98304
  int n = o >> 14;
  int l = (o >> 6) & 255;
  int m = o & 63;
  int i1 = l >> 4, j1 = l & 15;
  int bi = m >> 3, bj = m & 7;
  float s = 0.f;
#pragma unroll
  for (int rh = 0; rh < 2; ++rh)
#pragma unroll
    for (int rw = 0; rw < 2; ++rw) {
      int i2 = bi * 2 + rh, j2 = bj * 2 + rw;
      int idx = (i1 - i2 + 15) * 31 + (j1 - j2 + 15);
      s += pos[idx * 6 + n];
    }
  rpb[o] = s * 0.25f;
}

// pt[c][k] = proj_w[k][c]  (full transposed projection, 180x180)
__global__ void pt_kernel(const float* __restrict__ pjw, float* __restrict__ pt) {
  int i = blockIdx.x * 256 + threadIdx.x;
  if (i >= 180 * 180) return;
  int c = i / 180, k = i % 180;
  pt[c * 180 + k] = pjw[k * 180 + c];
}

// ======================= DFE stage 1: t1 = leaky(x @ W1 + b1), 180->36 ======
__global__ __launch_bounds__(256) void dfe1_kernel(const float* __restrict__ x,
                                                   const float* __restrict__ w1,
                                                   const float* __restrict__ b1,
                                                   float* __restrict__ t1) {
  __shared__ float xt[256][36];
  int t = threadIdx.x;
  int p0 = blockIdx.x * 256;
  float acc[36];
#pragma unroll
  for (int j = 0; j < 36; ++j) acc[j] = 0.f;
  for (int kc = 0; kc < 5; ++kc) {
    __syncthreads();
    for (int idx = t; idx < 256 * 36; idx += 256) {
      int px = idx / 36, ci = idx % 36;
      xt[px][ci] = x[(p0 + px) * 180 + kc * 36 + ci];
    }
    __syncthreads();
    for (int ci = 0; ci < 36; ++ci) {
      float v = xt[t][ci];
      const float* wr = &w1[(kc * 36 + ci) * 36];
#pragma unroll
      for (int j = 0; j < 36; ++j) acc[j] += v * wr[j];
    }
  }
  float* o = &t1[(p0 + t) * 36];
#pragma unroll
  for (int j = 0; j < 36; ++j) {
    float v = acc[j] + b1[j];
    o[j] = LEAKY(v);
  }
}

// ======================= DFE stage 2: 3x3 conv 36->36 + leaky ===============
__global__ __launch_bounds__(256) void dfe2_kernel(const float* __restrict__ t1,
                                                   const float* __restrict__ w2,
                                                   const float* __restrict__ b2,
                                                   float* __restrict__ t2) {
  __shared__ float halo[18][18][36];
  int t = threadIdx.x;
  int blk = blockIdx.x;
  int img = blk >> 8;
  int rem = blk & 255;
  int ty0 = (rem >> 4) << 4;
  int tx0 = (rem & 15) << 4;
  for (int idx = t; idx < 18 * 18 * 36; idx += 256) {
    int ci = idx % 36;
    int xx = (idx / 36) % 18;
    int yy = idx / (36 * 18);
    int gy = ty0 + yy - 1;
    int gx = tx0 + xx - 1;
    float v = 0.f;
    if (gy >= 0 && gy < 256 && gx >= 0 && gx < 256)
      v = t1[((img * 256 + gy) * 256 + gx) * 36 + ci];
    halo[yy][xx][ci] = v;
  }
  __syncthreads();
  int ly = t >> 4, lx = t & 15;
  float acc[36];
#pragma unroll
  for (int j = 0; j < 36; ++j) acc[j] = 0.f;
#pragma unroll
  for (int kh = 0; kh < 3; ++kh)
#pragma unroll
    for (int kw = 0; kw < 3; ++kw) {
      for (int ci = 0; ci < 36; ++ci) {
        float v = halo[ly + kh][lx + kw][ci];
        const float* wr = &w2[((kh * 3 + kw) * 36 + ci) * 36];
#pragma unroll
        for (int j = 0; j < 36; ++j) acc[j] += v * wr[j];
      }
    }
  float* o = &t2[((img * 256 + ty0 + ly) * 256 + tx0 + lx) * 36];
#pragma unroll
  for (int j = 0; j < 36; ++j) {
    float v = acc[j] + b2[j];
    o[j] = LEAKY(v);
  }
}

// ======== DFE stage 3: qv = (t2@W3 + b3) * (x@Wl + bl) =====================
// 256-px blocks, 16px x 12co per thread: 7 b128 per 192 FMA -> VALU-bound.
// Single acc array; linear phases -> epilogue1 (qv = accL + bl, frees regs);
// conv phase -> epilogue2 RMW (qv = (accC + b3) * qv, same-thread, L2-hot).
__global__ __launch_bounds__(256, 2) void dfe3_kernel(const float* __restrict__ x,
                                                      const float* __restrict__ t2,
                                                      const float* __restrict__ w3,
                                                      const float* __restrict__ b3,
                                                      const float* __restrict__ wl,
                                                      const float* __restrict__ bl,
                                                      float* __restrict__ qv) {
  __shared__ __align__(16) float As[36 * 260];       // [ci][px0..255], pad 260
  __shared__ __align__(16) float Bs[36 * 180 + 16];  // [ci][co] linear (+pad)
  int t = threadIdx.x;
  int tx = t & 15;   // co-group: co = tx*12 (tx==15 -> pad, guarded)
  int ty = t >> 4;   // px-group: px = ty*16 .. +15
  int p0 = blockIdx.x * 256;

  const float4* xf4  = (const float4*)x;
  const float4* t2f4 = (const float4*)t2;
  const float4* wlf4 = (const float4*)wl;
  const float4* w3f4 = (const float4*)w3;
  float4* Bs4 = (float4*)Bs;

  // A tile = 256 px x 9 f4 = 2304 f4 (9/thread); B = 1620 f4 (7th partial)
  auto stageA_x = [&](int kb) {
    float4 r[9];
#pragma unroll
    for (int c = 0; c < 9; ++c) {
      int idx = t + c * 256;
      int px = idx / 9, ca = idx - px * 9;
      r[c] = xf4[(size_t)(p0 + px) * 45 + kb + ca];
    }
#pragma unroll
    for (int c = 0; c < 9; ++c) {
      int idx = t + c * 256;
      int px = idx / 9, ca = idx - px * 9;
      As[(ca * 4 + 0) * 260 + px] = r[c].x;
      As[(ca * 4 + 1) * 260 + px] = r[c].y;
      As[(ca * 4 + 2) * 260 + px] = r[c].z;
      As[(ca * 4 + 3) * 260 + px] = r[c].w;
    }
  };
  auto stageA_t2 = [&]() {
    float4 r[9];
#pragma unroll
    for (int c = 0; c < 9; ++c) {
      int idx = t + c * 256;
      int px = idx / 9, ca = idx - px * 9;
      r[c] = t2f4[(size_t)(p0 + px) * 9 + ca];
    }
#pragma unroll
    for (int c = 0; c < 9; ++c) {
      int idx = t + c * 256;
      int px = idx / 9, ca = idx - px * 9;
      As[(ca * 4 + 0) * 260 + px] = r[c].x;
      As[(ca * 4 + 1) * 260 + px] = r[c].y;
      As[(ca * 4 + 2) * 260 + px] = r[c].z;
      As[(ca * 4 + 3) * 260 + px] = r[c].w;
    }
  };
  auto stageB = [&](const float4* src, int kw) {
    float4 r[7];
#pragma unroll
    for (int c = 0; c < 7; ++c) {
      int idx = t + c * 256;
      if (idx < 1620) r[c] = src[kw + idx];
    }
#pragma unroll
    for (int c = 0; c < 7; ++c) {
      int idx = t + c * 256;
      if (idx < 1620) Bs4[idx] = r[c];
    }
  };

  auto compute36 = [&](float acc[16][12]) {
    for (int ci = 0; ci < 36; ++ci) {
      const float4* ap = (const float4*)&As[ci * 260 + ty * 16];
      float4 A0 = ap[0], A1 = ap[1], A2 = ap[2], A3 = ap[3];
      const float* bp = &Bs[ci * 180 + tx * 12];
      float4 B0 = *(const float4*)bp;
      float4 B1 = *(const float4*)(bp + 4);
      float4 B2 = *(const float4*)(bp + 8);
      float av[16] = {A0.x, A0.y, A0.z, A0.w, A1.x, A1.y, A1.z, A1.w,
                      A2.x, A2.y, A2.z, A2.w, A3.x, A3.y, A3.z, A3.w};
      float bv[12] = {B0.x, B0.y, B0.z, B0.w, B1.x, B1.y, B1.z, B1.w,
                      B2.x, B2.y, B2.z, B2.w};
#pragma unroll
      for (int r = 0; r < 16; ++r)
#pragma unroll
        for (int j = 0; j < 12; ++j) acc[r][j] += av[r] * bv[j];
    }
  };

  float acc[16][12];
#pragma unroll
  for (int r = 0; r < 16; ++r)
#pragma unroll
    for (int j = 0; j < 12; ++j) acc[r][j] = 0.f;

  // ---- linear phases: K = 180 in 5 chunks ----
#pragma unroll 1
  for (int p = 0; p < 5; ++p) {
    __syncthreads();
    stageA_x(p * 9);
    stageB(wlf4, p * 1620);
    __syncthreads();
    compute36(acc);
  }

  // epilogue1: qv = accL + bl  (frees acc for conv)
  if (tx < 15) {
#pragma unroll
    for (int r = 0; r < 16; ++r) {
      int base = (p0 + ty * 16 + r) * 180 + tx * 12;
#pragma unroll
      for (int j = 0; j < 12; ++j) qv[base + j] = acc[r][j] + bl[tx * 12 + j];
    }
  }

  // ---- conv phase: K = 36 ----
#pragma unroll
  for (int r = 0; r < 16; ++r)
#pragma unroll
    for (int j = 0; j < 12; ++j) acc[r][j] = 0.f;
  __syncthreads();
  stageA_t2();
  stageB(w3f4, 0);
  __syncthreads();
  compute36(acc);

  // epilogue2: qv = (accC + b3) * qv  (same-thread RMW, L2-hot)
  if (tx < 15) {
#pragma unroll
    for (int r = 0; r < 16; ++r) {
      int base = (p0 + ty * 16 + r) * 180 + tx * 12;
#pragma unroll
      for (int j = 0; j < 12; ++j) {
        float lp = qv[base + j];
        qv[base + j] = (acc[r][j] + b3[tx * 12 + j]) * lp;
      }
    }
  }
}

// ========== spatial attention + first projection half (writes out) ==========
// Round-9 structure + G-TRICK: x_sp[l] = (1/15) G q[l] + sum_m rpb[l,m] vp[m],
// G = Vp^T Vp (15x15 per window-head, built cooperatively in LDS). Removes the
// per-m dot product entirely: R-loop is pure independent FMA (s = rpb value).
__global__ __launch_bounds__(256, 4) void att_sp_kernel(
    const float* __restrict__ qv, const float* __restrict__ slw,
    const float* __restrict__ slb, const float* __restrict__ rpb,
    const float* __restrict__ pt, const float* __restrict__ pb,
    float* __restrict__ out) {
  __shared__ __align__(16) float vp[6][64][16];  // 24.6 KB
  __shared__ float xsp[128][91];                 // 46.6 KB (odd stride)
  __shared__ __align__(16) float G[6][15][16];   // 5.6 KB  (total ~75 KB)
  int t = threadIdx.x;
  int wb = blockIdx.x;
  int b = wb >> 8, wi = (wb >> 4) & 15, wj = wb & 15;
  int wbase = (b * 256 + wi * 16) * 256 + wj * 16;  // pixel index of token 0
  float wsl0 = slw[0], wsl1 = slw[1], wsl2 = slw[2], wsl3 = slw[3];
  float bsl = slb[0];

  for (int idx = t; idx < 6 * 64 * 16; idx += 256) {
    int n = idx >> 10;
    int m = (idx >> 4) & 63;
    int ch = idx & 15;
    float s = 0.f;
    if (ch < 15) {
      int bi = m >> 3, bj = m & 7;
      int pa00 = (wbase + (bi * 2) * 256 + bj * 2) * 180 + 90 + n * 15 + ch;
      s = qv[pa00] * wsl0;
      s += qv[pa00 + 180] * wsl1;
      s += qv[pa00 + 256 * 180] * wsl2;
      s += qv[pa00 + 257 * 180] * wsl3;
      s += bsl;
    }
    vp[n][m][ch] = s;
  }
  __syncthreads();

  // ---- G build: G[n][i][j] = sum_m vp[n][m][i]*vp[n][m][j]  (90 threads) ---
  if (t < 90) {
    int n = t / 15, i = t - n * 15;
    float acc[15];
#pragma unroll
    for (int j = 0; j < 15; ++j) acc[j] = 0.f;
#pragma unroll 4
    for (int m = 0; m < 64; ++m) {
      float vi = vp[n][m][i];
      const float4* vr = (const float4*)(&vp[n][m][0]);
      float4 v0 = vr[0], v1 = vr[1], v2 = vr[2], v3 = vr[3];
      acc[0] += vi * v0.x; acc[1] += vi * v0.y; acc[2] += vi * v0.z; acc[3] += vi * v0.w;
      acc[4] += vi * v1.x; acc[5] += vi * v1.y; acc[6] += vi * v1.z; acc[7] += vi * v1.w;
      acc[8] += vi * v2.x; acc[9] += vi * v2.y; acc[10] += vi * v2.z; acc[11] += vi * v2.w;
      acc[12] += vi * v3.x; acc[13] += vi * v3.y; acc[14] += vi * v3.z;
    }
#pragma unroll
    for (int j = 0; j < 15; ++j) G[n][i][j] = acc[j];
    G[n][i][15] = 0.f;
  }
  __syncthreads();

  int lt = t & 127;
  int hg = t >> 7;
  const float inv15 = 1.f / 15.f;

#pragma unroll 1
  for (int half = 0; half < 2; ++half) {
    int l = half * 128 + lt;
    int pa = (wbase + (l >> 4) * 256 + (l & 15)) * 180;
#pragma unroll 1
    for (int nn = 0; nn < 3; ++nn) {
      int n = hg * 3 + nn;
      float qh[15];
#pragma unroll
      for (int c = 0; c < 15; ++c) qh[c] = qv[pa + n * 15 + c] * inv15;
      float xs[15];
#pragma unroll
      for (int c = 0; c < 15; ++c) xs[c] = 0.f;
      // ---- Gq term: xs += G^T qh  (G symmetric; rows broadcast from LDS) ---
#pragma unroll 3
      for (int d = 0; d < 15; ++d) {
        float qd = qh[d];
        const float4* gr = (const float4*)(&G[n][d][0]);
        float4 g0 = gr[0], g1 = gr[1], g2 = gr[2], g3 = gr[3];
        xs[0] += qd * g0.x; xs[1] += qd * g0.y; xs[2] += qd * g0.z; xs[3] += qd * g0.w;
        xs[4] += qd * g1.x; xs[5] += qd * g1.y; xs[6] += qd * g1.z; xs[7] += qd * g1.w;
        xs[8] += qd * g2.x; xs[9] += qd * g2.y; xs[10] += qd * g2.z; xs[11] += qd * g2.w;
        xs[12] += qd * g3.x; xs[13] += qd * g3.y; xs[14] += qd * g3.z;
      }
      // ---- R term: xs += sum_m rpb[l,m] * vp[m]  (no dot, pure FMA) --------
      const float* rp = &rpb[(n * 256 + l) * 64];
#pragma unroll 4
      for (int m4 = 0; m4 < 16; ++m4) {
        float4 rpv = *(const float4*)(rp + m4 * 4);
        float rparr[4] = {rpv.x, rpv.y, rpv.z, rpv.w};
#pragma unroll
        for (int mm = 0; mm < 4; ++mm) {
          const float4* vr = (const float4*)(&vp[n][m4 * 4 + mm][0]);
          float4 v0 = vr[0], v1 = vr[1], v2 = vr[2], v3 = vr[3];
          float s = rparr[mm];
          xs[0] += s * v0.x; xs[1] += s * v0.y; xs[2] += s * v0.z; xs[3] += s * v0.w;
          xs[4] += s * v1.x; xs[5] += s * v1.y; xs[6] += s * v1.z; xs[7] += s * v1.w;
          xs[8] += s * v2.x; xs[9] += s * v2.y; xs[10] += s * v2.z; xs[11] += s * v2.w;
          xs[12] += s * v3.x; xs[13] += s * v3.y; xs[14] += s * v3.z;
        }
      }
#pragma unroll
      for (int c = 0; c < 15; ++c) xsp[lt][n * 15 + c] = xs[c];
    }
    __syncthreads();
    // projection: wave w -> k-block w*45, lane = token (chupd pattern)
    {
      int lane = t & 63;
      int w4 = __builtin_amdgcn_readfirstlane(t >> 6);
      int k0 = w4 * 45;
      const float* ptb = pt + k0;
#pragma unroll 1
      for (int tok2 = 0; tok2 < 2; ++tok2) {
        int tt = tok2 * 64 + lane;
        int l2 = half * 128 + tt;
        int pa2 = (wbase + (l2 >> 4) * 256 + (l2 & 15)) * 180 + k0;
        float pacc[45];
#pragma unroll
        for (int j = 0; j < 45; ++j) pacc[j] = pb[k0 + j];
#pragma unroll 2
        for (int c = 0; c < 90; ++c) {
          float xv = xsp[tt][c];
          const float* prw = ptb + c * 180;  // wave-uniform, contiguous 45
#pragma unroll
          for (int j = 0; j < 45; ++j) pacc[j] += xv * prw[j];
        }
        float* op = out + pa2;
#pragma unroll
        for (int j = 0; j < 45; ++j) op[j] = pacc[j];
      }
    }
    __syncthreads();
  }
}

// ========== channel attention A: cmap then M = P2*cmap per window ===========
__global__ __launch_bounds__(256, 2) void cmapM_kernel(const float* __restrict__ qv,
                                                       const float* __restrict__ p2t,
                                                       float* __restrict__ M) {
  __shared__ float cmt[90][91];   // 32.8 KB
  __shared__ float bufA[32][97];  // 12.4 KB
  __shared__ float vtt[32][97];   // 12.4 KB
  int t = threadIdx.x;
  int wb = blockIdx.x;
  int b = wb >> 8, wi = (wb >> 4) & 15, wj = wb & 15;
  int wbase = (b * 256 + wi * 16) * 256 + wj * 16;

  int tx = t & 15, ty = t >> 4;
  float acc[6][6];
#pragma unroll
  for (int i = 0; i < 6; ++i)
#pragma unroll
    for (int j = 0; j < 6; ++j) acc[i][j] = 0.f;

#pragma unroll 1
  for (int ck = 0; ck < 8; ++ck) {
    __syncthreads();
    for (int idx = t; idx < 32 * 97; idx += 256) {
      int l = idx / 97, c = idx % 97;
      int gl = ck * 32 + l;
      int pa = (wbase + (gl >> 4) * 256 + (gl & 15)) * 180;
      bufA[l][c] = (c < 90) ? qv[pa + c] : 0.f;
      vtt[l][c] = (c < 90) ? qv[pa + 90 + c] : 0.f;
    }
    __syncthreads();
    for (int lk = 0; lk < 32; ++lk) {
      float aa[6], bb[6];
#pragma unroll
      for (int i = 0; i < 6; ++i) aa[i] = bufA[lk][tx * 6 + i];
#pragma unroll
      for (int j = 0; j < 6; ++j) bb[j] = vtt[lk][ty * 6 + j];
#pragma unroll
      for (int i = 0; i < 6; ++i)
#pragma unroll
        for (int j = 0; j < 6; ++j) acc[i][j] += aa[i] * bb[j];
    }
  }
  __syncthreads();
  if (tx < 15 && ty < 15) {
#pragma unroll
    for (int i = 0; i < 6; ++i)
#pragma unroll
      for (int j = 0; j < 6; ++j) cmt[tx * 6 + i][ty * 6 + j] = acc[i][j] * (1.f / 256.f);
  }
  __syncthreads();

  int lane = t & 63;
  int kq = __builtin_amdgcn_readfirstlane(t >> 6);
  int k0 = kq * 45;
  int d0 = lane;
  int d1 = lane + 64;
  int d1c = (d1 < 90) ? d1 : 0;
  float m0[45], m1[45];
#pragma unroll
  for (int j = 0; j < 45; ++j) { m0[j] = 0.f; m1[j] = 0.f; }
#pragma unroll 1
  for (int c = 0; c < 90; ++c) {
    const float* pr = p2t + c * 180 + k0;
    float v0 = cmt[c][d0];
    float v1 = cmt[c][d1c];
#pragma unroll
    for (int j = 0; j < 45; ++j) {
      float p = pr[j];
      m0[j] += p * v0;
      m1[j] += p * v1;
    }
  }
  float* M0 = M + (size_t)wb * 16200 + d0 * 180 + k0;
#pragma unroll
  for (int j = 0; j < 45; ++j) M0[j] = m0[j];
  if (d1 < 90) {
    float* M1 = M + (size_t)wb * 16200 + d1 * 180 + k0;
#pragma unroll
    for (int j = 0; j < 45; ++j) M1[j] = m1[j];
  }
}

// ========== channel attention B: out[l] += M * v[l]  ========================
__global__ __launch_bounds__(256, 4) void chupd_kernel(const float* __restrict__ qv,
                                                       const float* __restrict__ M,
                                                       float* __restrict__ out) {
  __shared__ float vt[64][91];  // 23.3 KB
  int bid = blockIdx.x;
  int wb = bid >> 2, grp = bid & 3;
  int b = wb >> 8, wi = (wb >> 4) & 15, wj = wb & 15;
  int wbase = (b * 256 + wi * 16) * 256 + wj * 16;
  int t = threadIdx.x;

  for (int idx = t; idx < 64 * 90; idx += 256) {
    int l = idx / 90, d = idx - l * 90;
    int gl = grp * 64 + l;
    int pa = (wbase + (gl >> 4) * 256 + (gl & 15)) * 180;
    vt[l][d] = qv[pa + 90 + d];
  }
  __syncthreads();

  int l = t & 63;
  int kq = __builtin_amdgcn_readfirstlane(t >> 6);
  int k0 = kq * 45;
  const float* Mw = M + (size_t)wb * 16200;
  float pacc[45];
#pragma unroll
  for (int j = 0; j < 45; ++j) pacc[j] = 0.f;
#pragma unroll 2
  for (int d = 0; d < 90; ++d) {
    const float* mr = Mw + d * 180 + k0;
    float vl = vt[l][d];
#pragma unroll
    for (int j = 0; j < 45; ++j) pacc[j] += mr[j] * vl;
  }
  int gl = grp * 64 + l;
  int pa = (wbase + (gl >> 4) * 256 + (gl & 15)) * 180 + k0;
#pragma unroll
  for (int j = 0; j < 45; ++j) out[pa + j] += pacc[j];
}

// ============================== launcher ====================================
extern "C" void kernel_launch(void* const* d_in, const int* in_sizes, int n_in,
                              void* d_out, int out_size, void* d_ws, size_t ws_size,
                              hipStream_t stream) {
  (void)in_sizes; (void)n_in; (void)out_size; (void)ws_size;
  const float* x   = (const float*)d_in[0];
  const float* w1  = (const float*)d_in[1];
  const float* b1  = (const float*)d_in[2];
  const float* w2  = (const float*)d_in[3];
  const float* b2  = (const float*)d_in[4];
  const float* w3  = (const float*)d_in[5];
  const float* b3  = (const float*)d_in[6];
  const float* wl  = (const float*)d_in[7];
  const float* bl  = (const float*)d_in[8];
  const float* slw = (const float*)d_in[9];
  const float* slb = (const float*)d_in[10];
  const float* pw0 = (const float*)d_in[11];
  const float* pb0 = (const float*)d_in[12];
  const float* g1  = (const float*)d_in[13];
  const float* be1 = (const float*)d_in[14];
  const float* mw1 = (const float*)d_in[15];
  const float* mb1 = (const float*)d_in[16];
  const float* g2  = (const float*)d_in[17];
  const float* be2 = (const float*)d_in[18];
  const float* mw2 = (const float*)d_in[19];
  const float* mb2 = (const float*)d_in[20];
  const float* g3  = (const float*)d_in[21];
  const float* be3 = (const float*)d_in[22];
  const float* mw3 = (const float*)d_in[23];
  const float* mb3 = (const float*)d_in[24];
  const float* pjw = (const float*)d_in[25];
  const float* pjb = (const float*)d_in[26];
  float* out = (float*)d_out;
  float* ws  = (float*)d_ws;

  float* qv  = ws;                      // 47185920 floats
  float* t1  = ws + 47185920;           // 9437184
  float* t2  = t1 + 9437184;            // 9437184
  float* pos = t2 + 9437184;            // 5766 (padded to 5768)
  float* rpb = pos + 5768;              // 98304
  float* M   = t1;                      // reuses t1 (dead after dfe3)
  float* pt  = t1 + 18874368 - 32768;   // 32400 used

  pos_mlp_kernel<<<4, 256, 0, stream>>>(pw0, pb0, g1, be1, mw1, mb1,
                                        g2, be2, mw2, mb2, g3, be3, mw3, mb3, pos);
  rpb_kernel<<<384, 256, 0, stream>>>(pos, rpb);
  dfe1_kernel<<<1024, 256, 0, stream>>>(x, w1, b1, t1);
  dfe2_kernel<<<1024, 256, 0, stream>>>(t1, w2, b2, t2);
  dfe3_kernel<<<1024, 256, 0, stream>>>(x, t2, w3, b3, wl, bl, qv);
  pt_kernel<<<127, 256, 0, stream>>>(pjw, pt);  // after dfe3 (overwrites t2 tail)
  att_sp_kernel<<<1024, 256, 0, stream>>>(qv, slw, slb, rpb, pt, pjb, out);
  cmapM_kernel<<<1024, 256, 0, stream>>>(qv, pt + 90 * 180, M);
  chupd_kernel<<<4096, 256, 0, stream>>>(qv, M, out);
}

// Round 15
// 1415.103 us; speedup vs baseline: 1.0212x; 1.0212x over previous
//
#include <hip/hip_runtime.h>

#define LEAKY(v) ((v) > 0.f ? (v) : 0.2f * (v))

// ======================= pos-bias MLP (961 rows, tiny) =======================
__device__ __forceinline__ void ln_relu11(float* p, const float* __restrict__ g,
                                          const float* __restrict__ b) {
  float mu = 0.f;
#pragma unroll
  for (int j = 0; j < 11; ++j) mu += p[j];
  mu *= (1.f / 11.f);
  float var = 0.f;
#pragma unroll
  for (int j = 0; j < 11; ++j) { float d = p[j] - mu; var += d * d; }
  var *= (1.f / 11.f);
  float inv = 1.f / sqrtf(var + 1e-5f);
#pragma unroll
  for (int j = 0; j < 11; ++j) {
    float v = (p[j] - mu) * inv * g[j] + b[j];
    p[j] = v > 0.f ? v : 0.f;
  }
}

__global__ void pos_mlp_kernel(
    const float* __restrict__ w0, const float* __restrict__ b0,
    const float* __restrict__ g1, const float* __restrict__ be1,
    const float* __restrict__ w1, const float* __restrict__ b1,
    const float* __restrict__ g2, const float* __restrict__ be2,
    const float* __restrict__ w2, const float* __restrict__ b2,
    const float* __restrict__ g3, const float* __restrict__ be3,
    const float* __restrict__ w3, const float* __restrict__ b3,
    float* __restrict__ pos_out) {
  int r = blockIdx.x * 256 + threadIdx.x;
  if (r >= 961) return;
  float bh = (float)(r / 31 - 15);
  float bw = (float)(r % 31 - 15);
  float p[11], q[11];
#pragma unroll
  for (int j = 0; j < 11; ++j) p[j] = bh * w0[2 * j] + bw * w0[2 * j + 1] + b0[j];
  ln_relu11(p, g1, be1);
#pragma unroll
  for (int j = 0; j < 11; ++j) {
    float s = b1[j];
#pragma unroll
    for (int k = 0; k < 11; ++k) s += p[k] * w1[j * 11 + k];
    q[j] = s;
  }
  ln_relu11(q, g2, be2);
#pragma unroll
  for (int j = 0; j < 11; ++j) {
    float s = b2[j];
#pragma unroll
    for (int k = 0; k < 11; ++k) s += q[k] * w2[j * 11 + k];
    p[j] = s;
  }
  ln_relu11(p, g3, be3);
#pragma unroll
  for (int n = 0; n < 6; ++n) {
    float s = b3[n];
#pragma unroll
    for (int k = 0; k < 11; ++k) s += p[k] * w3[n * 11 + k];
    pos_out[r * 6 + n] = s;
  }
}

// rpb[n][l][m] = mean over 2x2 of pos[rel_idx][n]   (6*256*64 elements)
__global__ void rpb_kernel(const float* __restrict__ pos, float* __restrict__ rpb) {
  int o = blockIdx.x * 256 + threadIdx.x;  // < 98304
  int n = o >> 14;
  int l = (o >> 6) & 255;
  int m = o & 63;
  int i1 = l >> 4, j1 = l & 15;
  int bi = m >> 3, bj = m & 7;
  float s = 0.f;
#pragma unroll
  for (int rh = 0; rh < 2; ++rh)
#pragma unroll
    for (int rw = 0; rw < 2; ++rw) {
      int i2 = bi * 2 + rh, j2 = bj * 2 + rw;
      int idx = (i1 - i2 + 15) * 31 + (j1 - j2 + 15);
      s += pos[idx * 6 + n];
    }
  rpb[o] = s * 0.25f;
}

// pt[c][k] = proj_w[k][c]  (full transposed projection, 180x180)
__global__ void pt_kernel(const float* __restrict__ pjw, float* __restrict__ pt) {
  int i = blockIdx.x * 256 + threadIdx.x;
  if (i >= 180 * 180) return;
  int c = i / 180, k = i % 180;
  pt[c * 180 + k] = pjw[k * 180 + c];
}

// ======================= DFE stage 1: t1 = leaky(x @ W1 + b1), 180->36 ======
__global__ __launch_bounds__(256) void dfe1_kernel(const float* __restrict__ x,
                                                   const float* __restrict__ w1,
                                                   const float* __restrict__ b1,
                                                   float* __restrict__ t1) {
  __shared__ float xt[256][36];
  int t = threadIdx.x;
  int p0 = blockIdx.x * 256;
  float acc[36];
#pragma unroll
  for (int j = 0; j < 36; ++j) acc[j] = 0.f;
  for (int kc = 0; kc < 5; ++kc) {
    __syncthreads();
    for (int idx = t; idx < 256 * 36; idx += 256) {
      int px = idx / 36, ci = idx % 36;
      xt[px][ci] = x[(p0 + px) * 180 + kc * 36 + ci];
    }
    __syncthreads();
    for (int ci = 0; ci < 36; ++ci) {
      float v = xt[t][ci];
      const float* wr = &w1[(kc * 36 + ci) * 36];
#pragma unroll
      for (int j = 0; j < 36; ++j) acc[j] += v * wr[j];
    }
  }
  float* o = &t1[(p0 + t) * 36];
#pragma unroll
  for (int j = 0; j < 36; ++j) {
    float v = acc[j] + b1[j];
    o[j] = LEAKY(v);
  }
}

// ======================= DFE stage 2: 3x3 conv 36->36 + leaky ===============
__global__ __launch_bounds__(256) void dfe2_kernel(const float* __restrict__ t1,
                                                   const float* __restrict__ w2,
                                                   const float* __restrict__ b2,
                                                   float* __restrict__ t2) {
  __shared__ float halo[18][18][36];
  int t = threadIdx.x;
  int blk = blockIdx.x;
  int img = blk >> 8;
  int rem = blk & 255;
  int ty0 = (rem >> 4) << 4;
  int tx0 = (rem & 15) << 4;
  for (int idx = t; idx < 18 * 18 * 36; idx += 256) {
    int ci = idx % 36;
    int xx = (idx / 36) % 18;
    int yy = idx / (36 * 18);
    int gy = ty0 + yy - 1;
    int gx = tx0 + xx - 1;
    float v = 0.f;
    if (gy >= 0 && gy < 256 && gx >= 0 && gx < 256)
      v = t1[((img * 256 + gy) * 256 + gx) * 36 + ci];
    halo[yy][xx][ci] = v;
  }
  __syncthreads();
  int ly = t >> 4, lx = t & 15;
  float acc[36];
#pragma unroll
  for (int j = 0; j < 36; ++j) acc[j] = 0.f;
#pragma unroll
  for (int kh = 0; kh < 3; ++kh)
#pragma unroll
    for (int kw = 0; kw < 3; ++kw) {
      for (int ci = 0; ci < 36; ++ci) {
        float v = halo[ly + kh][lx + kw][ci];
        const float* wr = &w2[((kh * 3 + kw) * 36 + ci) * 36];
#pragma unroll
        for (int j = 0; j < 36; ++j) acc[j] += v * wr[j];
      }
    }
  float* o = &t2[((img * 256 + ty0 + ly) * 256 + tx0 + lx) * 36];
#pragma unroll
  for (int j = 0; j < 36; ++j) {
    float v = acc[j] + b2[j];
    o[j] = LEAKY(v);
  }
}

// ======== DFE stage 3: qv = (t2@W3 + b3) * (x@Wl + bl) =====================
// Round-13 tile (128px, 8px x 12co, T14 prefetch) with A staged in two
// ci-halves: As shrinks 19->10.3 KB, total LDS 36.4 KB -> 3-4 blocks/CU.
__global__ __launch_bounds__(256, 3) void dfe3_kernel(const float* __restrict__ x,
                                                      const float* __restrict__ t2,
                                                      const float* __restrict__ w3,
                                                      const float* __restrict__ b3,
                                                      const float* __restrict__ wl,
                                                      const float* __restrict__ bl,
                                                      float* __restrict__ qv) {
  __shared__ __align__(16) float As[20 * 132];       // [ci_local][px] 10.3 KB
  __shared__ __align__(16) float Bs[36 * 180 + 16];  // [ci][co] linear, 26 KB
  int t = threadIdx.x;
  int tx = t & 15;   // co = tx*12 (tx==15 -> pad, guarded)
  int ty = t >> 4;   // px = ty*8 .. +7
  int p0 = blockIdx.x * 128;

  // A half0 = ca 0..3 (ci 0..15): 512 f4, 2/thread
  int pH0a = t >> 2,          cH0a = t & 3;
  int pH0b = (t + 256) >> 2,  cH0b = (t + 256) & 3;
  // A half1 = ca 4..8 (ci 16..35): 640 f4, 2.5/thread
  int pH1a = t / 5,           cH1a = t % 5;
  int pH1b = (t + 256) / 5,   cH1b = (t + 256) % 5;
  int pH1c = (t + 512) / 5,   cH1c = (t + 512) % 5;  // t < 128 only

  const float4* xf4  = (const float4*)x;
  const float4* t2f4 = (const float4*)t2;
  const float4* wlf4 = (const float4*)wl;
  const float4* w3f4 = (const float4*)w3;
  float4* Bs4 = (float4*)Bs;

  float4 a0, a1, a2;
  float4 bF0, bF1, bF2, bF3, bF4, bF5, bF6;
  a2 = make_float4(0.f, 0.f, 0.f, 0.f);
  bF6 = make_float4(0.f, 0.f, 0.f, 0.f);

  auto scatterA = [&](int row, int pa, float4 v) {
    As[(row + 0) * 132 + pa] = v.x;
    As[(row + 1) * 132 + pa] = v.y;
    As[(row + 2) * 132 + pa] = v.z;
    As[(row + 3) * 132 + pa] = v.w;
  };
  auto writeAh0 = [&]() {
    scatterA(cH0a * 4, pH0a, a0);
    scatterA(cH0b * 4, pH0b, a1);
  };
  auto writeAh1 = [&]() {
    scatterA(cH1a * 4, pH1a, a0);
    scatterA(cH1b * 4, pH1b, a1);
    if (t < 128) scatterA(cH1c * 4, pH1c, a2);
  };
  auto writeB = [&]() {
    Bs4[t] = bF0;
    Bs4[t + 256] = bF1;
    Bs4[t + 512] = bF2;
    Bs4[t + 768] = bF3;
    Bs4[t + 1024] = bF4;
    Bs4[t + 1280] = bF5;
    if (t < 84) Bs4[t + 1536] = bF6;
  };

  auto issueB = [&](const float4* src, int kw) {
    bF0 = src[kw + t];
    bF1 = src[kw + t + 256];
    bF2 = src[kw + t + 512];
    bF3 = src[kw + t + 768];
    bF4 = src[kw + t + 1024];
    bF5 = src[kw + t + 1280];
    if (t < 84) bF6 = src[kw + t + 1536];
  };
  auto issueAh0_x = [&](int kb) {
    a0 = xf4[(size_t)(p0 + pH0a) * 45 + kb + cH0a];
    a1 = xf4[(size_t)(p0 + pH0b) * 45 + kb + cH0b];
  };
  auto issueAh1_x = [&](int kb) {
    a0 = xf4[(size_t)(p0 + pH1a) * 45 + kb + 4 + cH1a];
    a1 = xf4[(size_t)(p0 + pH1b) * 45 + kb + 4 + cH1b];
    if (t < 128) a2 = xf4[(size_t)(p0 + pH1c) * 45 + kb + 4 + cH1c];
  };
  auto issueAh0_t2 = [&]() {
    a0 = t2f4[(size_t)(p0 + pH0a) * 9 + cH0a];
    a1 = t2f4[(size_t)(p0 + pH0b) * 9 + cH0b];
  };
  auto issueAh1_t2 = [&]() {
    a0 = t2f4[(size_t)(p0 + pH1a) * 9 + 4 + cH1a];
    a1 = t2f4[(size_t)(p0 + pH1b) * 9 + 4 + cH1b];
    if (t < 128) a2 = t2f4[(size_t)(p0 + pH1c) * 9 + 4 + cH1c];
  };

  float acc[8][12];
#pragma unroll
  for (int r = 0; r < 8; ++r)
#pragma unroll
    for (int j = 0; j < 12; ++j) acc[r][j] = 0.f;

  auto compute = [&](int nci, int hbase) {
    for (int ci = 0; ci < nci; ++ci) {
      const float4* ap = (const float4*)&As[ci * 132 + ty * 8];
      float4 A0 = ap[0], A1 = ap[1];
      const float* bp = &Bs[(hbase + ci) * 180 + tx * 12];
      float4 B0 = *(const float4*)bp;
      float4 B1 = *(const float4*)(bp + 4);
      float4 B2 = *(const float4*)(bp + 8);
      float av[8] = {A0.x, A0.y, A0.z, A0.w, A1.x, A1.y, A1.z, A1.w};
      float bv[12] = {B0.x, B0.y, B0.z, B0.w, B1.x, B1.y, B1.z, B1.w,
                      B2.x, B2.y, B2.z, B2.w};
#pragma unroll
      for (int r = 0; r < 8; ++r)
#pragma unroll
        for (int j = 0; j < 12; ++j) acc[r][j] += av[r] * bv[j];
    }
  };

  // ---- prologue: issue B(0) + A-half0(0) ----
  issueB(wlf4, 0);
  issueAh0_x(0);

  // ---- linear phases ----
#pragma unroll 1
  for (int p = 0; p < 5; ++p) {
    __syncthreads();
    writeB();
    writeAh0();
    __syncthreads();
    issueAh1_x(p * 9);
    compute(16, 0);
    __syncthreads();
    writeAh1();
    __syncthreads();
    if (p < 4) { issueB(wlf4, (p + 1) * 1620); issueAh0_x((p + 1) * 9); }
    else       { issueB(w3f4, 0);              issueAh0_t2(); }
    compute(20, 16);
  }

  // epilogue1: qv = accL + bl  (frees acc for conv)
  if (tx < 15) {
#pragma unroll
    for (int r = 0; r < 8; ++r) {
      int base = (p0 + ty * 8 + r) * 180 + tx * 12;
#pragma unroll
      for (int j = 0; j < 12; ++j) qv[base + j] = acc[r][j] + bl[tx * 12 + j];
    }
  }

  // ---- conv phase ----
#pragma unroll
  for (int r = 0; r < 8; ++r)
#pragma unroll
    for (int j = 0; j < 12; ++j) acc[r][j] = 0.f;
  __syncthreads();
  writeB();
  writeAh0();
  __syncthreads();
  issueAh1_t2();
  compute(16, 0);
  __syncthreads();
  writeAh1();
  __syncthreads();
  compute(20, 16);

  // epilogue2: qv = (accC + b3) * qv  (same-thread RMW, L2-hot)
  if (tx < 15) {
#pragma unroll
    for (int r = 0; r < 8; ++r) {
      int base = (p0 + ty * 8 + r) * 180 + tx * 12;
#pragma unroll
      for (int j = 0; j < 12; ++j) {
        float lp = qv[base + j];
        qv[base + j] = (acc[r][j] + b3[tx * 12 + j]) * lp;
      }
    }
  }
}

// ========== spatial attention + first projection half (writes out) ==========
// Round-13: G-TRICK. x_sp[l] = (1/15) G q[l] + sum_m rpb[l,m] vp[m].
__global__ __launch_bounds__(256, 4) void att_sp_kernel(
    const float* __restrict__ qv, const float* __restrict__ slw,
    const float* __restrict__ slb, const float* __restrict__ rpb,
    const float* __restrict__ pt, const float* __restrict__ pb,
    float* __restrict__ out) {
  __shared__ __align__(16) float vp[6][64][16];  // 24.6 KB
  __shared__ float xsp[128][91];                 // 46.6 KB (odd stride)
  __shared__ __align__(16) float G[6][15][16];   // 5.6 KB  (total ~75 KB)
  int t = threadIdx.x;
  int wb = blockIdx.x;
  int b = wb >> 8, wi = (wb >> 4) & 15, wj = wb & 15;
  int wbase = (b * 256 + wi * 16) * 256 + wj * 16;  // pixel index of token 0
  float wsl0 = slw[0], wsl1 = slw[1], wsl2 = slw[2], wsl3 = slw[3];
  float bsl = slb[0];

  for (int idx = t; idx < 6 * 64 * 16; idx += 256) {
    int n = idx >> 10;
    int m = (idx >> 4) & 63;
    int ch = idx & 15;
    float s = 0.f;
    if (ch < 15) {
      int bi = m >> 3, bj = m & 7;
      int pa00 = (wbase + (bi * 2) * 256 + bj * 2) * 180 + 90 + n * 15 + ch;
      s = qv[pa00] * wsl0;
      s += qv[pa00 + 180] * wsl1;
      s += qv[pa00 + 256 * 180] * wsl2;
      s += qv[pa00 + 257 * 180] * wsl3;
      s += bsl;
    }
    vp[n][m][ch] = s;
  }
  __syncthreads();

  // ---- G build: G[n][i][j] = sum_m vp[n][m][i]*vp[n][m][j]  (90 threads) ---
  if (t < 90) {
    int n = t / 15, i = t - n * 15;
    float acc[15];
#pragma unroll
    for (int j = 0; j < 15; ++j) acc[j] = 0.f;
#pragma unroll 4
    for (int m = 0; m < 64; ++m) {
      float vi = vp[n][m][i];
      const float4* vr = (const float4*)(&vp[n][m][0]);
      float4 v0 = vr[0], v1 = vr[1], v2 = vr[2], v3 = vr[3];
      acc[0] += vi * v0.x; acc[1] += vi * v0.y; acc[2] += vi * v0.z; acc[3] += vi * v0.w;
      acc[4] += vi * v1.x; acc[5] += vi * v1.y; acc[6] += vi * v1.z; acc[7] += vi * v1.w;
      acc[8] += vi * v2.x; acc[9] += vi * v2.y; acc[10] += vi * v2.z; acc[11] += vi * v2.w;
      acc[12] += vi * v3.x; acc[13] += vi * v3.y; acc[14] += vi * v3.z;
    }
#pragma unroll
    for (int j = 0; j < 15; ++j) G[n][i][j] = acc[j];
    G[n][i][15] = 0.f;
  }
  __syncthreads();

  int lt = t & 127;
  int hg = t >> 7;
  const float inv15 = 1.f / 15.f;

#pragma unroll 1
  for (int half = 0; half < 2; ++half) {
    int l = half * 128 + lt;
    int pa = (wbase + (l >> 4) * 256 + (l & 15)) * 180;
#pragma unroll 1
    for (int nn = 0; nn < 3; ++nn) {
      int n = hg * 3 + nn;
      float qh[15];
#pragma unroll
      for (int c = 0; c < 15; ++c) qh[c] = qv[pa + n * 15 + c] * inv15;
      float xs[15];
#pragma unroll
      for (int c = 0; c < 15; ++c) xs[c] = 0.f;
      // ---- Gq term ----
#pragma unroll 3
      for (int d = 0; d < 15; ++d) {
        float qd = qh[d];
        const float4* gr = (const float4*)(&G[n][d][0]);
        float4 g0 = gr[0], g1 = gr[1], g2 = gr[2], g3 = gr[3];
        xs[0] += qd * g0.x; xs[1] += qd * g0.y; xs[2] += qd * g0.z; xs[3] += qd * g0.w;
        xs[4] += qd * g1.x; xs[5] += qd * g1.y; xs[6] += qd * g1.z; xs[7] += qd * g1.w;
        xs[8] += qd * g2.x; xs[9] += qd * g2.y; xs[10] += qd * g2.z; xs[11] += qd * g2.w;
        xs[12] += qd * g3.x; xs[13] += qd * g3.y; xs[14] += qd * g3.z;
      }
      // ---- R term ----
      const float* rp = &rpb[(n * 256 + l) * 64];
#pragma unroll 4
      for (int m4 = 0; m4 < 16; ++m4) {
        float4 rpv = *(const float4*)(rp + m4 * 4);
        float rparr[4] = {rpv.x, rpv.y, rpv.z, rpv.w};
#pragma unroll
        for (int mm = 0; mm < 4; ++mm) {
          const float4* vr = (const float4*)(&vp[n][m4 * 4 + mm][0]);
          float4 v0 = vr[0], v1 = vr[1], v2 = vr[2], v3 = vr[3];
          float s = rparr[mm];
          xs[0] += s * v0.x; xs[1] += s * v0.y; xs[2] += s * v0.z; xs[3] += s * v0.w;
          xs[4] += s * v1.x; xs[5] += s * v1.y; xs[6] += s * v1.z; xs[7] += s * v1.w;
          xs[8] += s * v2.x; xs[9] += s * v2.y; xs[10] += s * v2.z; xs[11] += s * v2.w;
          xs[12] += s * v3.x; xs[13] += s * v3.y; xs[14] += s * v3.z;
        }
      }
#pragma unroll
      for (int c = 0; c < 15; ++c) xsp[lt][n * 15 + c] = xs[c];
    }
    __syncthreads();
    // projection: wave w -> k-block w*45, lane = token (chupd pattern)
    {
      int lane = t & 63;
      int w4 = __builtin_amdgcn_readfirstlane(t >> 6);
      int k0 = w4 * 45;
      const float* ptb = pt + k0;
#pragma unroll 1
      for (int tok2 = 0; tok2 < 2; ++tok2) {
        int tt = tok2 * 64 + lane;
        int l2 = half * 128 + tt;
        int pa2 = (wbase + (l2 >> 4) * 256 + (l2 & 15)) * 180 + k0;
        float pacc[45];
#pragma unroll
        for (int j = 0; j < 45; ++j) pacc[j] = pb[k0 + j];
#pragma unroll 2
        for (int c = 0; c < 90; ++c) {
          float xv = xsp[tt][c];
          const float* prw = ptb + c * 180;  // wave-uniform, contiguous 45
#pragma unroll
          for (int j = 0; j < 45; ++j) pacc[j] += xv * prw[j];
        }
        float* op = out + pa2;
#pragma unroll
        for (int j = 0; j < 45; ++j) op[j] = pacc[j];
      }
    }
    __syncthreads();
  }
}

// ========== channel attention A: cmap then M = P2*cmap per window ===========
__global__ __launch_bounds__(256, 2) void cmapM_kernel(const float* __restrict__ qv,
                                                       const float* __restrict__ p2t,
                                                       float* __restrict__ M) {
  __shared__ float cmt[90][91];   // 32.8 KB
  __shared__ float bufA[32][97];  // 12.4 KB
  __shared__ float vtt[32][97];   // 12.4 KB
  int t = threadIdx.x;
  int wb = blockIdx.x;
  int b = wb >> 8, wi = (wb >> 4) & 15, wj = wb & 15;
  int wbase = (b * 256 + wi * 16) * 256 + wj * 16;

  int tx = t & 15, ty = t >> 4;
  float acc[6][6];
#pragma unroll
  for (int i = 0; i < 6; ++i)
#pragma unroll
    for (int j = 0; j < 6; ++j) acc[i][j] = 0.f;

#pragma unroll 1
  for (int ck = 0; ck < 8; ++ck) {
    __syncthreads();
    for (int idx = t; idx < 32 * 97; idx += 256) {
      int l = idx / 97, c = idx % 97;
      int gl = ck * 32 + l;
      int pa = (wbase + (gl >> 4) * 256 + (gl & 15)) * 180;
      bufA[l][c] = (c < 90) ? qv[pa + c] : 0.f;
      vtt[l][c] = (c < 90) ? qv[pa + 90 + c] : 0.f;
    }
    __syncthreads();
    for (int lk = 0; lk < 32; ++lk) {
      float aa[6], bb[6];
#pragma unroll
      for (int i = 0; i < 6; ++i) aa[i] = bufA[lk][tx * 6 + i];
#pragma unroll
      for (int j = 0; j < 6; ++j) bb[j] = vtt[lk][ty * 6 + j];
#pragma unroll
      for (int i = 0; i < 6; ++i)
#pragma unroll
        for (int j = 0; j < 6; ++j) acc[i][j] += aa[i] * bb[j];
    }
  }
  __syncthreads();
  if (tx < 15 && ty < 15) {
#pragma unroll
    for (int i = 0; i < 6; ++i)
#pragma unroll
      for (int j = 0; j < 6; ++j) cmt[tx * 6 + i][ty * 6 + j] = acc[i][j] * (1.f / 256.f);
  }
  __syncthreads();

  int lane = t & 63;
  int kq = __builtin_amdgcn_readfirstlane(t >> 6);
  int k0 = kq * 45;
  int d0 = lane;
  int d1 = lane + 64;
  int d1c = (d1 < 90) ? d1 : 0;
  float m0[45], m1[45];
#pragma unroll
  for (int j = 0; j < 45; ++j) { m0[j] = 0.f; m1[j] = 0.f; }
#pragma unroll 1
  for (int c = 0; c < 90; ++c) {
    const float* pr = p2t + c * 180 + k0;
    float v0 = cmt[c][d0];
    float v1 = cmt[c][d1c];
#pragma unroll
    for (int j = 0; j < 45; ++j) {
      float p = pr[j];
      m0[j] += p * v0;
      m1[j] += p * v1;
    }
  }
  float* M0 = M + (size_t)wb * 16200 + d0 * 180 + k0;
#pragma unroll
  for (int j = 0; j < 45; ++j) M0[j] = m0[j];
  if (d1 < 90) {
    float* M1 = M + (size_t)wb * 16200 + d1 * 180 + k0;
#pragma unroll
    for (int j = 0; j < 45; ++j) M1[j] = m1[j];
  }
}

// ========== channel attention B: out[l] += M * v[l]  ========================
__global__ __launch_bounds__(256, 4) void chupd_kernel(const float* __restrict__ qv,
                                                       const float* __restrict__ M,
                                                       float* __restrict__ out) {
  __shared__ float vt[64][91];  // 23.3 KB
  int bid = blockIdx.x;
  int wb = bid >> 2, grp = bid & 3;
  int b = wb >> 8, wi = (wb >> 4) & 15, wj = wb & 15;
  int wbase = (b * 256 + wi * 16) * 256 + wj * 16;
  int t = threadIdx.x;

  for (int idx = t; idx < 64 * 90; idx += 256) {
    int l = idx / 90, d = idx - l * 90;
    int gl = grp * 64 + l;
    int pa = (wbase + (gl >> 4) * 256 + (gl & 15)) * 180;
    vt[l][d] = qv[pa + 90 + d];
  }
  __syncthreads();

  int l = t & 63;
  int kq = __builtin_amdgcn_readfirstlane(t >> 6);
  int k0 = kq * 45;
  const float* Mw = M + (size_t)wb * 16200;
  float pacc[45];
#pragma unroll
  for (int j = 0; j < 45; ++j) pacc[j] = 0.f;
#pragma unroll 2
  for (int d = 0; d < 90; ++d) {
    const float* mr = Mw + d * 180 + k0;
    float vl = vt[l][d];
#pragma unroll
    for (int j = 0; j < 45; ++j) pacc[j] += mr[j] * vl;
  }
  int gl = grp * 64 + l;
  int pa = (wbase + (gl >> 4) * 256 + (gl & 15)) * 180 + k0;
#pragma unroll
  for (int j = 0; j < 45; ++j) out[pa + j] += pacc[j];
}

// ============================== launcher ====================================
extern "C" void kernel_launch(void* const* d_in, const int* in_sizes, int n_in,
                              void* d_out, int out_size, void* d_ws, size_t ws_size,
                              hipStream_t stream) {
  (void)in_sizes; (void)n_in; (void)out_size; (void)ws_size;
  const float* x   = (const float*)d_in[0];
  const float* w1  = (const float*)d_in[1];
  const float* b1  = (const float*)d_in[2];
  const float* w2  = (const float*)d_in[3];
  const float* b2  = (const float*)d_in[4];
  const float* w3  = (const float*)d_in[5];
  const float* b3  = (const float*)d_in[6];
  const float* wl  = (const float*)d_in[7];
  const float* bl  = (const float*)d_in[8];
  const float* slw = (const float*)d_in[9];
  const float* slb = (const float*)d_in[10];
  const float* pw0 = (const float*)d_in[11];
  const float* pb0 = (const float*)d_in[12];
  const float* g1  = (const float*)d_in[13];
  const float* be1 = (const float*)d_in[14];
  const float* mw1 = (const float*)d_in[15];
  const float* mb1 = (const float*)d_in[16];
  const float* g2  = (const float*)d_in[17];
  const float* be2 = (const float*)d_in[18];
  const float* mw2 = (const float*)d_in[19];
  const float* mb2 = (const float*)d_in[20];
  const float* g3  = (const float*)d_in[21];
  const float* be3 = (const float*)d_in[22];
  const float* mw3 = (const float*)d_in[23];
  const float* mb3 = (const float*)d_in[24];
  const float* pjw = (const float*)d_in[25];
  const float* pjb = (const float*)d_in[26];
  float* out = (float*)d_out;
  float* ws  = (float*)d_ws;

  float* qv  = ws;                      // 47185920 floats
  float* t1  = ws + 47185920;           // 9437184
  float* t2  = t1 + 9437184;            // 9437184
  float* pos = t2 + 9437184;            // 5766 (padded to 5768)
  float* rpb = pos + 5768;              // 98304
  float* M   = t1;                      // reuses t1 (dead after dfe3)
  float* pt  = t1 + 18874368 - 32768;   // 32400 used

  pos_mlp_kernel<<<4, 256, 0, stream>>>(pw0, pb0, g1, be1, mw1, mb1,
                                        g2, be2, mw2, mb2, g3, be3, mw3, mb3, pos);
  rpb_kernel<<<384, 256, 0, stream>>>(pos, rpb);
  dfe1_kernel<<<1024, 256, 0, stream>>>(x, w1, b1, t1);
  dfe2_kernel<<<1024, 256, 0, stream>>>(t1, w2, b2, t2);
  dfe3_kernel<<<2048, 256, 0, stream>>>(x, t2, w3, b3, wl, bl, qv);
  pt_kernel<<<127, 256, 0, stream>>>(pjw, pt);  // after dfe3 (overwrites t2 tail)
  att_sp_kernel<<<1024, 256, 0, stream>>>(qv, slw, slb, rpb, pt, pjb, out);
  cmapM_kernel<<<1024, 256, 0, stream>>>(qv, pt + 90 * 180, M);
  chupd_kernel<<<4096, 256, 0, stream>>>(qv, M, out);
}

// Round 16
// 1336.803 us; speedup vs baseline: 1.0811x; 1.0586x over previous
//
#include <hip/hip_runtime.h>

#define LEAKY(v) ((v) > 0.f ? (v) : 0.2f * (v))

// ======================= pos-bias MLP (961 rows, tiny) =======================
__device__ __forceinline__ void ln_relu11(float* p, const float* __restrict__ g,
                                          const float* __restrict__ b) {
  float mu = 0.f;
#pragma unroll
  for (int j = 0; j < 11; ++j) mu += p[j];
  mu *= (1.f / 11.f);
  float var = 0.f;
#pragma unroll
  for (int j = 0; j < 11; ++j) { float d = p[j] - mu; var += d * d; }
  var *= (1.f / 11.f);
  float inv = 1.f / sqrtf(var + 1e-5f);
#pragma unroll
  for (int j = 0; j < 11; ++j) {
    float v = (p[j] - mu) * inv * g[j] + b[j];
    p[j] = v > 0.f ? v : 0.f;
  }
}

__global__ void pos_mlp_kernel(
    const float* __restrict__ w0, const float* __restrict__ b0,
    const float* __restrict__ g1, const float* __restrict__ be1,
    const float* __restrict__ w1, const float* __restrict__ b1,
    const float* __restrict__ g2, const float* __restrict__ be2,
    const float* __restrict__ w2, const float* __restrict__ b2,
    const float* __restrict__ g3, const float* __restrict__ be3,
    const float* __restrict__ w3, const float* __restrict__ b3,
    float* __restrict__ pos_out) {
  int r = blockIdx.x * 256 + threadIdx.x;
  if (r >= 961) return;
  float bh = (float)(r / 31 - 15);
  float bw = (float)(r % 31 - 15);
  float p[11], q[11];
#pragma unroll
  for (int j = 0; j < 11; ++j) p[j] = bh * w0[2 * j] + bw * w0[2 * j + 1] + b0[j];
  ln_relu11(p, g1, be1);
#pragma unroll
  for (int j = 0; j < 11; ++j) {
    float s = b1[j];
#pragma unroll
    for (int k = 0; k < 11; ++k) s += p[k] * w1[j * 11 + k];
    q[j] = s;
  }
  ln_relu11(q, g2, be2);
#pragma unroll
  for (int j = 0; j < 11; ++j) {
    float s = b2[j];
#pragma unroll
    for (int k = 0; k < 11; ++k) s += q[k] * w2[j * 11 + k];
    p[j] = s;
  }
  ln_relu11(p, g3, be3);
#pragma unroll
  for (int n = 0; n < 6; ++n) {
    float s = b3[n];
#pragma unroll
    for (int k = 0; k < 11; ++k) s += p[k] * w3[n * 11 + k];
    pos_out[r * 6 + n] = s;
  }
}

// rpb[n][l][m] = mean over 2x2 of pos[rel_idx][n]   (6*256*64 elements)
__global__ void rpb_kernel(const float* __restrict__ pos, float* __restrict__ rpb) {
  int o = blockIdx.x * 256 + threadIdx.x;  // < 98304
  int n = o >> 14;
  int l = (o >> 6) & 255;
  int m = o & 63;
  int i1 = l >> 4, j1 = l & 15;
  int bi = m >> 3, bj = m & 7;
  float s = 0.f;
#pragma unroll
  for (int rh = 0; rh < 2; ++rh)
#pragma unroll
    for (int rw = 0; rw < 2; ++rw) {
      int i2 = bi * 2 + rh, j2 = bj * 2 + rw;
      int idx = (i1 - i2 + 15) * 31 + (j1 - j2 + 15);
      s += pos[idx * 6 + n];
    }
  rpb[o] = s * 0.25f;
}

// pt[c][k] = proj_w[k][c]  (full transposed projection, 180x180)
__global__ void pt_kernel(const float* __restrict__ pjw, float* __restrict__ pt) {
  int i = blockIdx.x * 256 + threadIdx.x;
  if (i >= 180 * 180) return;
  int c = i / 180, k = i % 180;
  pt[c * 180 + k] = pjw[k * 180 + c];
}

// ======================= DFE stage 1: t1 = leaky(x @ W1 + b1), 180->36 ======
// xt padded to 37: stride-36 read was an 8-way bank conflict.
__global__ __launch_bounds__(256) void dfe1_kernel(const float* __restrict__ x,
                                                   const float* __restrict__ w1,
                                                   const float* __restrict__ b1,
                                                   float* __restrict__ t1) {
  __shared__ float xt[256][37];
  int t = threadIdx.x;
  int p0 = blockIdx.x * 256;
  float acc[36];
#pragma unroll
  for (int j = 0; j < 36; ++j) acc[j] = 0.f;
  for (int kc = 0; kc < 5; ++kc) {
    __syncthreads();
    for (int idx = t; idx < 256 * 36; idx += 256) {
      int px = idx / 36, ci = idx % 36;
      xt[px][ci] = x[(p0 + px) * 180 + kc * 36 + ci];
    }
    __syncthreads();
    for (int ci = 0; ci < 36; ++ci) {
      float v = xt[t][ci];
      const float* wr = &w1[(kc * 36 + ci) * 36];
#pragma unroll
      for (int j = 0; j < 36; ++j) acc[j] += v * wr[j];
    }
  }
  float* o = &t1[(p0 + t) * 36];
#pragma unroll
  for (int j = 0; j < 36; ++j) {
    float v = acc[j] + b1[j];
    o[j] = LEAKY(v);
  }
}

// ======================= DFE stage 2: 3x3 conv 36->36 + leaky ===============
// halo channel dim padded to 37: stride-36 read was an 8-way bank conflict.
__global__ __launch_bounds__(256) void dfe2_kernel(const float* __restrict__ t1,
                                                   const float* __restrict__ w2,
                                                   const float* __restrict__ b2,
                                                   float* __restrict__ t2) {
  __shared__ float halo[18][18][37];  // 47.9 KB
  int t = threadIdx.x;
  int blk = blockIdx.x;
  int img = blk >> 8;
  int rem = blk & 255;
  int ty0 = (rem >> 4) << 4;
  int tx0 = (rem & 15) << 4;
  for (int idx = t; idx < 18 * 18 * 36; idx += 256) {
    int ci = idx % 36;
    int xx = (idx / 36) % 18;
    int yy = idx / (36 * 18);
    int gy = ty0 + yy - 1;
    int gx = tx0 + xx - 1;
    float v = 0.f;
    if (gy >= 0 && gy < 256 && gx >= 0 && gx < 256)
      v = t1[((img * 256 + gy) * 256 + gx) * 36 + ci];
    halo[yy][xx][ci] = v;
  }
  __syncthreads();
  int ly = t >> 4, lx = t & 15;
  float acc[36];
#pragma unroll
  for (int j = 0; j < 36; ++j) acc[j] = 0.f;
#pragma unroll
  for (int kh = 0; kh < 3; ++kh)
#pragma unroll
    for (int kw = 0; kw < 3; ++kw) {
      for (int ci = 0; ci < 36; ++ci) {
        float v = halo[ly + kh][lx + kw][ci];
        const float* wr = &w2[((kh * 3 + kw) * 36 + ci) * 36];
#pragma unroll
        for (int j = 0; j < 36; ++j) acc[j] += v * wr[j];
      }
    }
  float* o = &t2[((img * 256 + ty0 + ly) * 256 + tx0 + lx) * 36];
#pragma unroll
  for (int j = 0; j < 36; ++j) {
    float v = acc[j] + b2[j];
    o[j] = LEAKY(v);
  }
}

// ======== DFE stage 3 (round-13 exact): 128px, 8px x 12co, T14 prefetch ====
__global__ __launch_bounds__(256, 2) void dfe3_kernel(const float* __restrict__ x,
                                                      const float* __restrict__ t2,
                                                      const float* __restrict__ w3,
                                                      const float* __restrict__ b3,
                                                      const float* __restrict__ wl,
                                                      const float* __restrict__ bl,
                                                      float* __restrict__ qv) {
  __shared__ __align__(16) float As[36 * 132];       // [ci][px], 128+4 pad
  __shared__ __align__(16) float Bs[36 * 180 + 16];  // [ci][co] linear (+pad)
  int t = threadIdx.x;
  int tx = t & 15;
  int ty = t >> 4;
  int p0 = blockIdx.x * 128;

  int pA0 = t / 9,           cA0 = t - pA0 * 9;
  int pA1 = (t + 256) / 9,   cA1 = (t + 256) - pA1 * 9;
  int pA2 = (t + 512) / 9,   cA2 = (t + 512) - pA2 * 9;
  int pA3 = (t + 768) / 9,   cA3 = (t + 768) - pA3 * 9;
  int pA4 = (t + 1024) / 9,  cA4 = (t + 1024) - pA4 * 9;
  const float4* xf4  = (const float4*)x;
  const float4* t2f4 = (const float4*)t2;
  const float4* wlf4 = (const float4*)wl;
  const float4* w3f4 = (const float4*)w3;
  float4* Bs4 = (float4*)Bs;

  float4 a0, a1, a2, a3, a4;
  float4 bF0, bF1, bF2, bF3, bF4, bF5, bF6;
  a4 = make_float4(0.f, 0.f, 0.f, 0.f);
  bF6 = make_float4(0.f, 0.f, 0.f, 0.f);

  auto scatterA = [&](int pa, int ca, float4 v) {
    As[(ca * 4 + 0) * 132 + pa] = v.x;
    As[(ca * 4 + 1) * 132 + pa] = v.y;
    As[(ca * 4 + 2) * 132 + pa] = v.z;
    As[(ca * 4 + 3) * 132 + pa] = v.w;
  };
  auto stage_write = [&]() {
    scatterA(pA0, cA0, a0);
    scatterA(pA1, cA1, a1);
    scatterA(pA2, cA2, a2);
    scatterA(pA3, cA3, a3);
    if (t < 128) scatterA(pA4, cA4, a4);
    Bs4[t] = bF0;
    Bs4[t + 256] = bF1;
    Bs4[t + 512] = bF2;
    Bs4[t + 768] = bF3;
    Bs4[t + 1024] = bF4;
    Bs4[t + 1280] = bF5;
    if (t < 84) Bs4[t + 1536] = bF6;
  };

  auto issue_lin = [&](int kc) {
    int kb = kc * 9;
    a0 = xf4[(size_t)(p0 + pA0) * 45 + kb + cA0];
    a1 = xf4[(size_t)(p0 + pA1) * 45 + kb + cA1];
    a2 = xf4[(size_t)(p0 + pA2) * 45 + kb + cA2];
    a3 = xf4[(size_t)(p0 + pA3) * 45 + kb + cA3];
    if (t < 128) a4 = xf4[(size_t)(p0 + pA4) * 45 + kb + cA4];
    int kw = kc * 1620;
    bF0 = wlf4[kw + t];
    bF1 = wlf4[kw + t + 256];
    bF2 = wlf4[kw + t + 512];
    bF3 = wlf4[kw + t + 768];
    bF4 = wlf4[kw + t + 1024];
    bF5 = wlf4[kw + t + 1280];
    if (t < 84) bF6 = wlf4[kw + t + 1536];
  };
  auto issue_conv = [&]() {
    a0 = t2f4[(size_t)(p0 + pA0) * 9 + cA0];
    a1 = t2f4[(size_t)(p0 + pA1) * 9 + cA1];
    a2 = t2f4[(size_t)(p0 + pA2) * 9 + cA2];
    a3 = t2f4[(size_t)(p0 + pA3) * 9 + cA3];
    if (t < 128) a4 = t2f4[(size_t)(p0 + pA4) * 9 + cA4];
    bF0 = w3f4[t];
    bF1 = w3f4[t + 256];
    bF2 = w3f4[t + 512];
    bF3 = w3f4[t + 768];
    bF4 = w3f4[t + 1024];
    bF5 = w3f4[t + 1280];
    if (t < 84) bF6 = w3f4[t + 1536];
  };

  auto compute36 = [&](float acc[8][12]) {
    for (int ci = 0; ci < 36; ++ci) {
      const float4* ap = (const float4*)&As[ci * 132 + ty * 8];
      float4 A0 = ap[0], A1 = ap[1];
      const float* bp = &Bs[ci * 180 + tx * 12];
      float4 B0 = *(const float4*)bp;
      float4 B1 = *(const float4*)(bp + 4);
      float4 B2 = *(const float4*)(bp + 8);
      float av[8] = {A0.x, A0.y, A0.z, A0.w, A1.x, A1.y, A1.z, A1.w};
      float bv[12] = {B0.x, B0.y, B0.z, B0.w, B1.x, B1.y, B1.z, B1.w,
                      B2.x, B2.y, B2.z, B2.w};
#pragma unroll
      for (int r = 0; r < 8; ++r)
#pragma unroll
        for (int j = 0; j < 12; ++j) acc[r][j] += av[r] * bv[j];
    }
  };

  issue_lin(0);
  float accL[8][12];
#pragma unroll
  for (int r = 0; r < 8; ++r)
#pragma unroll
    for (int j = 0; j < 12; ++j) accL[r][j] = 0.f;

#pragma unroll 1
  for (int p = 0; p < 5; ++p) {
    stage_write();
    __syncthreads();
    if (p < 4) issue_lin(p + 1); else issue_conv();
    compute36(accL);
    __syncthreads();
  }

  if (tx < 15) {
#pragma unroll
    for (int r = 0; r < 8; ++r) {
      int base = (p0 + ty * 8 + r) * 180 + tx * 12;
#pragma unroll
      for (int j = 0; j < 12; ++j) qv[base + j] = accL[r][j] + bl[tx * 12 + j];
    }
  }

  float accC[8][12];
#pragma unroll
  for (int r = 0; r < 8; ++r)
#pragma unroll
    for (int j = 0; j < 12; ++j) accC[r][j] = 0.f;
  stage_write();
  __syncthreads();
  compute36(accC);

  if (tx < 15) {
#pragma unroll
    for (int r = 0; r < 8; ++r) {
      int base = (p0 + ty * 8 + r) * 180 + tx * 12;
#pragma unroll
      for (int j = 0; j < 12; ++j) {
        float lp = qv[base + j];
        qv[base + j] = (accC[r][j] + b3[tx * 12 + j]) * lp;
      }
    }
  }
}

// ========== spatial attention + first projection half (writes out) ==========
// G-TRICK: x_sp[l] = (1/15) G q[l] + sum_m rpb[l,m] vp[m].
__global__ __launch_bounds__(256, 4) void att_sp_kernel(
    const float* __restrict__ qv, const float* __restrict__ slw,
    const float* __restrict__ slb, const float* __restrict__ rpb,
    const float* __restrict__ pt, const float* __restrict__ pb,
    float* __restrict__ out) {
  __shared__ __align__(16) float vp[6][64][16];  // 24.6 KB
  __shared__ float xsp[128][91];                 // 46.6 KB (odd stride)
  __shared__ __align__(16) float G[6][15][16];   // 5.6 KB  (total ~75 KB)
  int t = threadIdx.x;
  int wb = blockIdx.x;
  int b = wb >> 8, wi = (wb >> 4) & 15, wj = wb & 15;
  int wbase = (b * 256 + wi * 16) * 256 + wj * 16;  // pixel index of token 0
  float wsl0 = slw[0], wsl1 = slw[1], wsl2 = slw[2], wsl3 = slw[3];
  float bsl = slb[0];

  for (int idx = t; idx < 6 * 64 * 16; idx += 256) {
    int n = idx >> 10;
    int m = (idx >> 4) & 63;
    int ch = idx & 15;
    float s = 0.f;
    if (ch < 15) {
      int bi = m >> 3, bj = m & 7;
      int pa00 = (wbase + (bi * 2) * 256 + bj * 2) * 180 + 90 + n * 15 + ch;
      s = qv[pa00] * wsl0;
      s += qv[pa00 + 180] * wsl1;
      s += qv[pa00 + 256 * 180] * wsl2;
      s += qv[pa00 + 257 * 180] * wsl3;
      s += bsl;
    }
    vp[n][m][ch] = s;
  }
  __syncthreads();

  // ---- G build: G[n][i][j] = sum_m vp[n][m][i]*vp[n][m][j]  (90 threads) ---
  if (t < 90) {
    int n = t / 15, i = t - n * 15;
    float acc[15];
#pragma unroll
    for (int j = 0; j < 15; ++j) acc[j] = 0.f;
#pragma unroll 4
    for (int m = 0; m < 64; ++m) {
      float vi = vp[n][m][i];
      const float4* vr = (const float4*)(&vp[n][m][0]);
      float4 v0 = vr[0], v1 = vr[1], v2 = vr[2], v3 = vr[3];
      acc[0] += vi * v0.x; acc[1] += vi * v0.y; acc[2] += vi * v0.z; acc[3] += vi * v0.w;
      acc[4] += vi * v1.x; acc[5] += vi * v1.y; acc[6] += vi * v1.z; acc[7] += vi * v1.w;
      acc[8] += vi * v2.x; acc[9] += vi * v2.y; acc[10] += vi * v2.z; acc[11] += vi * v2.w;
      acc[12] += vi * v3.x; acc[13] += vi * v3.y; acc[14] += vi * v3.z;
    }
#pragma unroll
    for (int j = 0; j < 15; ++j) G[n][i][j] = acc[j];
    G[n][i][15] = 0.f;
  }
  __syncthreads();

  int lt = t & 127;
  int hg = t >> 7;
  const float inv15 = 1.f / 15.f;

#pragma unroll 1
  for (int half = 0; half < 2; ++half) {
    int l = half * 128 + lt;
    int pa = (wbase + (l >> 4) * 256 + (l & 15)) * 180;
#pragma unroll 1
    for (int nn = 0; nn < 3; ++nn) {
      int n = hg * 3 + nn;
      float qh[15];
#pragma unroll
      for (int c = 0; c < 15; ++c) qh[c] = qv[pa + n * 15 + c] * inv15;
      float xs[15];
#pragma unroll
      for (int c = 0; c < 15; ++c) xs[c] = 0.f;
      // ---- Gq term ----
#pragma unroll 3
      for (int d = 0; d < 15; ++d) {
        float qd = qh[d];
        const float4* gr = (const float4*)(&G[n][d][0]);
        float4 g0 = gr[0], g1 = gr[1], g2 = gr[2], g3 = gr[3];
        xs[0] += qd * g0.x; xs[1] += qd * g0.y; xs[2] += qd * g0.z; xs[3] += qd * g0.w;
        xs[4] += qd * g1.x; xs[5] += qd * g1.y; xs[6] += qd * g1.z; xs[7] += qd * g1.w;
        xs[8] += qd * g2.x; xs[9] += qd * g2.y; xs[10] += qd * g2.z; xs[11] += qd * g2.w;
        xs[12] += qd * g3.x; xs[13] += qd * g3.y; xs[14] += qd * g3.z;
      }
      // ---- R term ----
      const float* rp = &rpb[(n * 256 + l) * 64];
#pragma unroll 4
      for (int m4 = 0; m4 < 16; ++m4) {
        float4 rpv = *(const float4*)(rp + m4 * 4);
        float rparr[4] = {rpv.x, rpv.y, rpv.z, rpv.w};
#pragma unroll
        for (int mm = 0; mm < 4; ++mm) {
          const float4* vr = (const float4*)(&vp[n][m4 * 4 + mm][0]);
          float4 v0 = vr[0], v1 = vr[1], v2 = vr[2], v3 = vr[3];
          float s = rparr[mm];
          xs[0] += s * v0.x; xs[1] += s * v0.y; xs[2] += s * v0.z; xs[3] += s * v0.w;
          xs[4] += s * v1.x; xs[5] += s * v1.y; xs[6] += s * v1.z; xs[7] += s * v1.w;
          xs[8] += s * v2.x; xs[9] += s * v2.y; xs[10] += s * v2.z; xs[11] += s * v2.w;
          xs[12] += s * v3.x; xs[13] += s * v3.y; xs[14] += s * v3.z;
        }
      }
#pragma unroll
      for (int c = 0; c < 15; ++c) xsp[lt][n * 15 + c] = xs[c];
    }
    __syncthreads();
    // projection: wave w -> k-block w*45, lane = token (chupd pattern)
    {
      int lane = t & 63;
      int w4 = __builtin_amdgcn_readfirstlane(t >> 6);
      int k0 = w4 * 45;
      const float* ptb = pt + k0;
#pragma unroll 1
      for (int tok2 = 0; tok2 < 2; ++tok2) {
        int tt = tok2 * 64 + lane;
        int l2 = half * 128 + tt;
        int pa2 = (wbase + (l2 >> 4) * 256 + (l2 & 15)) * 180 + k0;
        float pacc[45];
#pragma unroll
        for (int j = 0; j < 45; ++j) pacc[j] = pb[k0 + j];
#pragma unroll 2
        for (int c = 0; c < 90; ++c) {
          float xv = xsp[tt][c];
          const float* prw = ptb + c * 180;  // wave-uniform, contiguous 45
#pragma unroll
          for (int j = 0; j < 45; ++j) pacc[j] += xv * prw[j];
        }
        float* op = out + pa2;
#pragma unroll
        for (int j = 0; j < 45; ++j) op[j] = pacc[j];
      }
    }
    __syncthreads();
  }
}

// ========== channel attention A: cmap then M = P2*cmap per window ===========
__global__ __launch_bounds__(256, 2) void cmapM_kernel(const float* __restrict__ qv,
                                                       const float* __restrict__ p2t,
                                                       float* __restrict__ M) {
  __shared__ float cmt[90][91];   // 32.8 KB
  __shared__ float bufA[32][97];  // 12.4 KB
  __shared__ float vtt[32][97];   // 12.4 KB
  int t = threadIdx.x;
  int wb = blockIdx.x;
  int b = wb >> 8, wi = (wb >> 4) & 15, wj = wb & 15;
  int wbase = (b * 256 + wi * 16) * 256 + wj * 16;

  int tx = t & 15, ty = t >> 4;
  float acc[6][6];
#pragma unroll
  for (int i = 0; i < 6; ++i)
#pragma unroll
    for (int j = 0; j < 6; ++j) acc[i][j] = 0.f;

#pragma unroll 1
  for (int ck = 0; ck < 8; ++ck) {
    __syncthreads();
    for (int idx = t; idx < 32 * 97; idx += 256) {
      int l = idx / 97, c = idx % 97;
      int gl = ck * 32 + l;
      int pa = (wbase + (gl >> 4) * 256 + (gl & 15)) * 180;
      bufA[l][c] = (c < 90) ? qv[pa + c] : 0.f;
      vtt[l][c] = (c < 90) ? qv[pa + 90 + c] : 0.f;
    }
    __syncthreads();
    for (int lk = 0; lk < 32; ++lk) {
      float aa[6], bb[6];
#pragma unroll
      for (int i = 0; i < 6; ++i) aa[i] = bufA[lk][tx * 6 + i];
#pragma unroll
      for (int j = 0; j < 6; ++j) bb[j] = vtt[lk][ty * 6 + j];
#pragma unroll
      for (int i = 0; i < 6; ++i)
#pragma unroll
        for (int j = 0; j < 6; ++j) acc[i][j] += aa[i] * bb[j];
    }
  }
  __syncthreads();
  if (tx < 15 && ty < 15) {
#pragma unroll
    for (int i = 0; i < 6; ++i)
#pragma unroll
      for (int j = 0; j < 6; ++j) cmt[tx * 6 + i][ty * 6 + j] = acc[i][j] * (1.f / 256.f);
  }
  __syncthreads();

  int lane = t & 63;
  int kq = __builtin_amdgcn_readfirstlane(t >> 6);
  int k0 = kq * 45;
  int d0 = lane;
  int d1 = lane + 64;
  int d1c = (d1 < 90) ? d1 : 0;
  float m0[45], m1[45];
#pragma unroll
  for (int j = 0; j < 45; ++j) { m0[j] = 0.f; m1[j] = 0.f; }
#pragma unroll 1
  for (int c = 0; c < 90; ++c) {
    const float* pr = p2t + c * 180 + k0;
    float v0 = cmt[c][d0];
    float v1 = cmt[c][d1c];
#pragma unroll
    for (int j = 0; j < 45; ++j) {
      float p = pr[j];
      m0[j] += p * v0;
      m1[j] += p * v1;
    }
  }
  float* M0 = M + (size_t)wb * 16200 + d0 * 180 + k0;
#pragma unroll
  for (int j = 0; j < 45; ++j) M0[j] = m0[j];
  if (d1 < 90) {
    float* M1 = M + (size_t)wb * 16200 + d1 * 180 + k0;
#pragma unroll
    for (int j = 0; j < 45; ++j) M1[j] = m1[j];
  }
}

// ========== channel attention B: out[l] += M * v[l]  ========================
__global__ __launch_bounds__(256, 4) void chupd_kernel(const float* __restrict__ qv,
                                                       const float* __restrict__ M,
                                                       float* __restrict__ out) {
  __shared__ float vt[64][91];  // 23.3 KB
  int bid = blockIdx.x;
  int wb = bid >> 2, grp = bid & 3;
  int b = wb >> 8, wi = (wb >> 4) & 15, wj = wb & 15;
  int wbase = (b * 256 + wi * 16) * 256 + wj * 16;
  int t = threadIdx.x;

  for (int idx = t; idx < 64 * 90; idx += 256) {
    int l = idx / 90, d = idx - l * 90;
    int gl = grp * 64 + l;
    int pa = (wbase + (gl >> 4) * 256 + (gl & 15)) * 180;
    vt[l][d] = qv[pa + 90 + d];
  }
  __syncthreads();

  int l = t & 63;
  int kq = __builtin_amdgcn_readfirstlane(t >> 6);
  int k0 = kq * 45;
  const float* Mw = M + (size_t)wb * 16200;
  float pacc[45];
#pragma unroll
  for (int j = 0; j < 45; ++j) pacc[j] = 0.f;
#pragma unroll 2
  for (int d = 0; d < 90; ++d) {
    const float* mr = Mw + d * 180 + k0;
    float vl = vt[l][d];
#pragma unroll
    for (int j = 0; j < 45; ++j) pacc[j] += mr[j] * vl;
  }
  int gl = grp * 64 + l;
  int pa = (wbase + (gl >> 4) * 256 + (gl & 15)) * 180 + k0;
#pragma unroll
  for (int j = 0; j < 45; ++j) out[pa + j] += pacc[j];
}

// ============================== launcher ====================================
extern "C" void kernel_launch(void* const* d_in, const int* in_sizes, int n_in,
                              void* d_out, int out_size, void* d_ws, size_t ws_size,
                              hipStream_t stream) {
  (void)in_sizes; (void)n_in; (void)out_size; (void)ws_size;
  const float* x   = (const float*)d_in[0];
  const float* w1  = (const float*)d_in[1];
  const float* b1  = (const float*)d_in[2];
  const float* w2  = (const float*)d_in[3];
  const float* b2  = (const float*)d_in[4];
  const float* w3  = (const float*)d_in[5];
  const float* b3  = (const float*)d_in[6];
  const float* wl  = (const float*)d_in[7];
  const float* bl  = (const float*)d_in[8];
  const float* slw = (const float*)d_in[9];
  const float* slb = (const float*)d_in[10];
  const float* pw0 = (const float*)d_in[11];
  const float* pb0 = (const float*)d_in[12];
  const float* g1  = (const float*)d_in[13];
  const float* be1 = (const float*)d_in[14];
  const float* mw1 = (const float*)d_in[15];
  const float* mb1 = (const float*)d_in[16];
  const float* g2  = (const float*)d_in[17];
  const float* be2 = (const float*)d_in[18];
  const float* mw2 = (const float*)d_in[19];
  const float* mb2 = (const float*)d_in[20];
  const float* g3  = (const float*)d_in[21];
  const float* be3 = (const float*)d_in[22];
  const float* mw3 = (const float*)d_in[23];
  const float* mb3 = (const float*)d_in[24];
  const float* pjw = (const float*)d_in[25];
  const float* pjb = (const float*)d_in[26];
  float* out = (float*)d_out;
  float* ws  = (float*)d_ws;

  float* qv  = ws;                      // 47185920 floats
  float* t1  = ws + 47185920;           // 9437184
  float* t2  = t1 + 9437184;            // 9437184
  float* pos = t2 + 9437184;            // 5766 (padded to 5768)
  float* rpb = pos + 5768;              // 98304
  float* M   = t1;                      // reuses t1 (dead after dfe3)
  float* pt  = t1 + 18874368 - 32768;   // 32400 used

  pos_mlp_kernel<<<4, 256, 0, stream>>>(pw0, pb0, g1, be1, mw1, mb1,
                                        g2, be2, mw2, mb2, g3, be3, mw3, mb3, pos);
  rpb_kernel<<<384, 256, 0, stream>>>(pos, rpb);
  dfe1_kernel<<<1024, 256, 0, stream>>>(x, w1, b1, t1);
  dfe2_kernel<<<1024, 256, 0, stream>>>(t1, w2, b2, t2);
  dfe3_kernel<<<2048, 256, 0, stream>>>(x, t2, w3, b3, wl, bl, qv);
  pt_kernel<<<127, 256, 0, stream>>>(pjw, pt);  // after dfe3 (overwrites t2 tail)
  att_sp_kernel<<<1024, 256, 0, stream>>>(qv, slw, slb, rpb, pt, pjb, out);
  cmapM_kernel<<<1024, 256, 0, stream>>>(qv, pt + 90 * 180, M);
  chupd_kernel<<<4096, 256, 0, stream>>>(qv, M, out);
}